// Round 1
// baseline (490.563 us; speedup 1.0000x reference)
//
#include <hip/hip_runtime.h>
#include <math.h>

typedef unsigned short u16;
typedef unsigned int u32;
typedef __bf16 bf16x8 __attribute__((ext_vector_type(8)));
typedef float f32x4 __attribute__((ext_vector_type(4)));

// B=4, L=2048, D_MODEL=512, D_INNER=1024, D_STATE=16, D_CONV=4, DT_RANK=32
#define LSEQ 2048
#define BL_TOT 8192            // B*L
#define NCHUNK 16
#define CHLEN 128

__device__ __forceinline__ float bf2f(u16 h) { return __uint_as_float(((u32)h) << 16); }
__device__ __forceinline__ u16 f2bf(float f) {
  u32 u = __float_as_uint(f);
  u32 r = (u + 0x7fffu + ((u >> 16) & 1u)) >> 16;
  return (u16)r;
}

// ---------------- cast f32 -> bf16 (vector x4) ----------------
__global__ __launch_bounds__(256) void cast_f32_bf16_kernel(
    const float* __restrict__ in, u16* __restrict__ out, int n4)
{
  const int i = blockIdx.x * 256 + threadIdx.x;
  if (i >= n4) return;
  const float4 v = ((const float4*)in)[i];
  uint2 o;
  o.x = (u32)f2bf(v.x) | ((u32)f2bf(v.y) << 16);
  o.y = (u32)f2bf(v.z) | ((u32)f2bf(v.w) << 16);
  ((uint2*)out)[i] = o;
}

// ---------------- bf16 MFMA GEMM: C[M,N] = A[M,K] * B[N,K]^T ----------------
// 128x128 tile, 4 waves (2x2 of 64x64), BK=32, one 16x16x32 MFMA K-step/tile.
// EPI: 0 = f32 store, 1 = bf16 store, 2 = softplus(acc + bias[n]) -> bf16
template<int EPI>
__global__ __launch_bounds__(256) void gemm_bf16_kernel(
    const u16* __restrict__ A, int lda,
    const u16* __restrict__ B, int ldb,
    void* __restrict__ C, int ldc,
    int N, int K, const float* __restrict__ bias)
{
  __shared__ u16 As[128][40];   // pad: 80B row stride (16B aligned, 8-bank spread)
  __shared__ u16 Bs[128][40];
  const int tid = threadIdx.x;
  const int row0 = blockIdx.y * 128;
  const int col0 = blockIdx.x * 128;
  const int wave = tid >> 6, lane = tid & 63;
  const int wr = (wave >> 1) * 64;   // wave row offset in tile
  const int wc = (wave & 1) * 64;    // wave col offset in tile
  const int lr = lane & 15, lk = lane >> 4;

  f32x4 acc[4][4] = {};

  for (int k0 = 0; k0 < K; k0 += 32) {
    __syncthreads();
    #pragma unroll
    for (int s = 0; s < 2; ++s) {
      const int slot = tid + s * 256;           // 512 slots of 8 bf16 (16B)
      const int r = slot >> 2, c8 = (slot & 3) << 3;
      *(int4*)&As[r][c8] = *(const int4*)(A + (size_t)(row0 + r) * lda + k0 + c8);
      const int nr = col0 + r;
      int4 bv = {0, 0, 0, 0};
      if (nr < N) bv = *(const int4*)(B + (size_t)nr * ldb + k0 + c8);
      *(int4*)&Bs[r][c8] = bv;
    }
    __syncthreads();
    bf16x8 af[4], bfr[4];
    #pragma unroll
    for (int i = 0; i < 4; ++i) {
      af[i]  = *(const bf16x8*)&As[wr + i * 16 + lr][lk * 8];  // A[m][k..k+7]
      bfr[i] = *(const bf16x8*)&Bs[wc + i * 16 + lr][lk * 8];  // B^T[n][k..k+7]
    }
    #pragma unroll
    for (int i = 0; i < 4; ++i)
      #pragma unroll
      for (int j = 0; j < 4; ++j)
        acc[i][j] = __builtin_amdgcn_mfma_f32_16x16x32_bf16(af[i], bfr[j], acc[i][j], 0, 0, 0);
  }

  // C/D layout (HW-verified): col = lane&15, row = (lane>>4)*4 + reg
  #pragma unroll
  for (int i = 0; i < 4; ++i) {
    #pragma unroll
    for (int j = 0; j < 4; ++j) {
      #pragma unroll
      for (int q = 0; q < 4; ++q) {
        const int r = row0 + wr + i * 16 + lk * 4 + q;
        const int c = col0 + wc + j * 16 + lr;
        if (c < N) {
          float v = acc[i][j][q];
          const size_t o = (size_t)r * ldc + c;
          if (EPI == 0) {
            ((float*)C)[o] = v;
          } else if (EPI == 1) {
            ((u16*)C)[o] = f2bf(v);
          } else {
            v += bias[c];
            v = (v > 20.f) ? v : log1pf(__expf(v));
            ((u16*)C)[o] = f2bf(v);
          }
        }
      }
    }
  }
}

// ---------------- depthwise causal conv1d (k=4) + SiLU ----------------
// x = xz[..., :1024] ; u[b,t,d] = silu(sum_k x[b,t-3+k,d]*cw[d,k] + cb[d])
__global__ __launch_bounds__(256) void conv_silu_kernel(
    const u16* __restrict__ xz, const float* __restrict__ cw,
    const float* __restrict__ cb, u16* __restrict__ u)
{
  const int idx = blockIdx.x * 256 + threadIdx.x;  // BL_TOT * 256 threads
  const int d4 = (idx & 255) << 2;
  const int bl = idx >> 8;            // b*L + t
  const int t = bl & (LSEQ - 1);
  float a0 = cb[d4], a1 = cb[d4 + 1], a2 = cb[d4 + 2], a3 = cb[d4 + 3];
  #pragma unroll
  for (int k = 0; k < 4; ++k) {
    const int tt = t - 3 + k;
    if (tt < 0) continue;
    const uint2 xv = *(const uint2*)(xz + (size_t)(bl - 3 + k) * 2048 + d4);
    a0 += __uint_as_float(xv.x << 16)         * cw[(d4 + 0) * 4 + k];
    a1 += __uint_as_float(xv.x & 0xffff0000u) * cw[(d4 + 1) * 4 + k];
    a2 += __uint_as_float(xv.y << 16)         * cw[(d4 + 2) * 4 + k];
    a3 += __uint_as_float(xv.y & 0xffff0000u) * cw[(d4 + 3) * 4 + k];
  }
  a0 = a0 / (1.f + __expf(-a0));
  a1 = a1 / (1.f + __expf(-a1));
  a2 = a2 / (1.f + __expf(-a2));
  a3 = a3 / (1.f + __expf(-a3));
  uint2 o;
  o.x = (u32)f2bf(a0) | ((u32)f2bf(a1) << 16);
  o.y = (u32)f2bf(a2) | ((u32)f2bf(a3) << 16);
  *(uint2*)(u + (size_t)bl * 1024 + d4) = o;
}

// ---------------- selective scan, chunked (16 chunks x 128) ----------------
// lane layout: 16 lanes per (b,d) channel, lane = state index n.
__global__ __launch_bounds__(256) void scan_pass1(
    const u16* __restrict__ delta, const u16* __restrict__ u,
    const u16* __restrict__ xdbl, const float* __restrict__ A_log,
    float* __restrict__ hend, float* __restrict__ sumdelta)
{
  const int blk = blockIdx.x;         // 4096 = 16 chunks * 256 groups
  const int chunk = blk >> 8;
  const int chgrp = blk & 255;
  const int tid = threadIdx.x;
  const int ch = chgrp * 16 + (tid >> 4);  // 0..4095 = b*1024+d
  const int n = tid & 15;
  const int b = ch >> 10, d = ch & 1023;
  const float A = -__expf(A_log[d * 16 + n]);
  float h = 0.f, sumd = 0.f;
  const size_t base = (size_t)b * LSEQ + chunk * CHLEN;
  const u16* dp = delta + base * 1024 + d;
  const u16* up = u + base * 1024 + d;
  const u16* bp = xdbl + base * 64 + 32 + n;
  for (int t = 0; t < CHLEN; ++t) {
    const float dt = bf2f(dp[(size_t)t * 1024]);
    const float ut = bf2f(up[(size_t)t * 1024]);
    const float bn = bf2f(bp[(size_t)t * 64]);
    h = h * __expf(dt * A) + dt * ut * bn;
    sumd += dt;
  }
  hend[((size_t)chunk * 4096 + ch) * 16 + n] = h;
  if (n == 0) sumdelta[chunk * 4096 + ch] = sumd;
}

__global__ __launch_bounds__(256) void scan_pass2(
    const float* __restrict__ A_log, const float* __restrict__ sumdelta,
    const float* __restrict__ hend, float* __restrict__ hinit)
{
  const int idx = blockIdx.x * 256 + threadIdx.x;  // 65536 = 4096 ch * 16 n
  const int ch = idx >> 4, n = idx & 15;
  const int d = ch & 1023;
  const float A = -__expf(A_log[d * 16 + n]);
  float h = 0.f;
  for (int c = 0; c < NCHUNK; ++c) {
    const size_t o = (size_t)c * 4096 + ch;
    hinit[o * 16 + n] = h;
    h = __expf(A * sumdelta[o]) * h + hend[o * 16 + n];
  }
}

// pass3: recompute with correct h_init, y = (<h,C> + u*D) * silu(z) -> bf16
// NOTE: y aliases delta (read-before-write per element within the same thread).
__global__ __launch_bounds__(256) void scan_pass3(
    const u16* __restrict__ delta, const u16* __restrict__ u,
    const u16* __restrict__ xdbl, const u16* __restrict__ xz,
    const float* __restrict__ A_log, const float* __restrict__ Dvec,
    const float* __restrict__ hinit, u16* __restrict__ y)
{
  const int blk = blockIdx.x;
  const int chunk = blk >> 8;
  const int chgrp = blk & 255;
  const int tid = threadIdx.x;
  const int ch = chgrp * 16 + (tid >> 4);
  const int n = tid & 15;
  const int b = ch >> 10, d = ch & 1023;
  const float A = -__expf(A_log[d * 16 + n]);
  const float Dd = Dvec[d];
  float h = hinit[((size_t)chunk * 4096 + ch) * 16 + n];
  const size_t base = (size_t)b * LSEQ + chunk * CHLEN;
  const u16* dp = delta + base * 1024 + d;
  const u16* up = u + base * 1024 + d;
  const u16* bp = xdbl + base * 64 + 32 + n;
  const u16* cp = xdbl + base * 64 + 48 + n;
  const u16* zp = xz + base * 2048 + 1024 + d;
  u16* yp = y + base * 1024 + d;
  for (int t = 0; t < CHLEN; ++t) {
    const float dt = bf2f(dp[(size_t)t * 1024]);
    const float ut = bf2f(up[(size_t)t * 1024]);
    const float bn = bf2f(bp[(size_t)t * 64]);
    const float cn = bf2f(cp[(size_t)t * 64]);
    h = h * __expf(dt * A) + dt * ut * bn;
    float pv = h * cn;
    pv += __shfl_xor(pv, 1);
    pv += __shfl_xor(pv, 2);
    pv += __shfl_xor(pv, 4);
    pv += __shfl_xor(pv, 8);
    if (n == 0) {
      const float z = bf2f(zp[(size_t)t * 2048]);
      const float yy = (pv + ut * Dd) * (z / (1.f + __expf(-z)));
      yp[(size_t)t * 1024] = f2bf(yy);
    }
  }
}

extern "C" void kernel_launch(void* const* d_in, const int* in_sizes, int n_in,
                              void* d_out, int out_size, void* d_ws, size_t ws_size,
                              hipStream_t stream)
{
  (void)in_sizes; (void)n_in; (void)out_size; (void)ws_size;
  const float* hs    = (const float*)d_in[0];
  const float* Win   = (const float*)d_in[1];
  const float* convw = (const float*)d_in[2];
  const float* convb = (const float*)d_in[3];
  const float* Wx    = (const float*)d_in[4];
  const float* Wdt   = (const float*)d_in[5];
  const float* bdt   = (const float*)d_in[6];
  const float* Alog  = (const float*)d_in[7];
  const float* Dv    = (const float*)d_in[8];
  const float* Wout  = (const float*)d_in[9];

  char* p = (char*)d_ws;
  auto take = [&](size_t bytes) -> char* {
    char* r = p; p += (bytes + 255) & ~(size_t)255; return r;
  };
  u16* hs_bf    = (u16*)take((size_t)BL_TOT * 512 * 2);
  u16* win_bf   = (u16*)take((size_t)2048 * 512 * 2);
  u16* wx_bf    = (u16*)take((size_t)64 * 1024 * 2);
  u16* wdt_bf   = (u16*)take((size_t)1024 * 32 * 2);
  u16* wout_bf  = (u16*)take((size_t)512 * 1024 * 2);
  u16* xz_bf    = (u16*)take((size_t)BL_TOT * 2048 * 2);
  u16* u_bf     = (u16*)take((size_t)BL_TOT * 1024 * 2);
  u16* xdbl_bf  = (u16*)take((size_t)BL_TOT * 64 * 2);
  u16* delta_bf = (u16*)take((size_t)BL_TOT * 1024 * 2);
  u16* y_bf     = delta_bf;  // alias (safe: read-before-write per element)
  float* hend   = (float*)take((size_t)NCHUNK * 4096 * 16 * 4);
  float* sumd   = (float*)take((size_t)NCHUNK * 4096 * 4);
  float* hinit  = (float*)take((size_t)NCHUNK * 4096 * 16 * 4);

  // input casts to bf16
  cast_f32_bf16_kernel<<<4096, 256, 0, stream>>>(hs, hs_bf, BL_TOT * 512 / 4);
  cast_f32_bf16_kernel<<<1024, 256, 0, stream>>>(Win, win_bf, 2048 * 512 / 4);
  cast_f32_bf16_kernel<<<64, 256, 0, stream>>>(Wx, wx_bf, 64 * 1024 / 4);
  cast_f32_bf16_kernel<<<32, 256, 0, stream>>>(Wdt, wdt_bf, 1024 * 32 / 4);
  cast_f32_bf16_kernel<<<512, 256, 0, stream>>>(Wout, wout_bf, 512 * 1024 / 4);

  // K1: xz = hs @ Win^T   (8192 x 2048, K=512)
  gemm_bf16_kernel<1><<<dim3(16, 64), 256, 0, stream>>>(
      hs_bf, 512, win_bf, 512, xz_bf, 2048, 2048, 512, nullptr);
  // conv + silu -> u (8192 x 1024)
  conv_silu_kernel<<<BL_TOT, 256, 0, stream>>>(xz_bf, convw, convb, u_bf);
  // x_dbl = u @ Wx^T (8192 x 64, K=1024)
  gemm_bf16_kernel<1><<<dim3(1, 64), 256, 0, stream>>>(
      u_bf, 1024, wx_bf, 1024, xdbl_bf, 64, 64, 1024, nullptr);
  // delta = softplus(dt_low @ Wdt^T + b_dt) (8192 x 1024, K=32)
  gemm_bf16_kernel<2><<<dim3(8, 64), 256, 0, stream>>>(
      xdbl_bf, 64, wdt_bf, 32, delta_bf, 1024, 1024, 32, bdt);
  // selective scan (chunked)
  scan_pass1<<<4096, 256, 0, stream>>>(delta_bf, u_bf, xdbl_bf, Alog, hend, sumd);
  scan_pass2<<<256, 256, 0, stream>>>(Alog, sumd, hend, hinit);
  scan_pass3<<<4096, 256, 0, stream>>>(delta_bf, u_bf, xdbl_bf, xz_bf, Alog, Dv, hinit, y_bf);
  // out = y @ Wout^T (8192 x 512, K=1024) -> f32
  gemm_bf16_kernel<0><<<dim3(4, 64), 256, 0, stream>>>(
      y_bf, 1024, wout_bf, 1024, d_out, 512, 512, 1024, nullptr);
}

// Round 2
// 389.759 us; speedup vs baseline: 1.2586x; 1.2586x over previous
//
#include <hip/hip_runtime.h>
#include <math.h>

typedef unsigned short u16;
typedef unsigned int u32;
typedef __bf16 bf16x8 __attribute__((ext_vector_type(8)));
typedef float f32x4 __attribute__((ext_vector_type(4)));

// B=4, L=2048, D_MODEL=512, D_INNER=1024, D_STATE=16, D_CONV=4, DT_RANK=32
#define LSEQ 2048
#define BL_TOT 8192            // B*L
#define NCHUNK 32
#define CHLEN 64

__device__ __forceinline__ float bf2f(u16 h) { return __uint_as_float(((u32)h) << 16); }
__device__ __forceinline__ u16 f2bf(float f) {
  u32 u = __float_as_uint(f);
  u32 r = (u + 0x7fffu + ((u >> 16) & 1u)) >> 16;
  return (u16)r;
}

// ---------------- cast f32 -> bf16 (vector x4) ----------------
__global__ __launch_bounds__(256) void cast_f32_bf16_kernel(
    const float* __restrict__ in, u16* __restrict__ out, int n4)
{
  const int i = blockIdx.x * 256 + threadIdx.x;
  if (i >= n4) return;
  const float4 v = ((const float4*)in)[i];
  uint2 o;
  o.x = (u32)f2bf(v.x) | ((u32)f2bf(v.y) << 16);
  o.y = (u32)f2bf(v.z) | ((u32)f2bf(v.w) << 16);
  ((uint2*)out)[i] = o;
}

// ---------------- cast bf16 -> f32 (vector x4) ----------------
__global__ __launch_bounds__(256) void cast_bf16_f32_kernel(
    const u16* __restrict__ in, float* __restrict__ out, int n4)
{
  const int i = blockIdx.x * 256 + threadIdx.x;
  if (i >= n4) return;
  const uint2 v = ((const uint2*)in)[i];
  float4 o;
  o.x = __uint_as_float(v.x << 16);
  o.y = __uint_as_float(v.x & 0xffff0000u);
  o.z = __uint_as_float(v.y << 16);
  o.w = __uint_as_float(v.y & 0xffff0000u);
  ((float4*)out)[i] = o;
}

// ---------------- bf16 MFMA GEMM: C[M,N] = A[M,K] * B[N,K]^T ----------------
// 128x128 tile, 4 waves (2x2 of 64x64), BK=32, one 16x16x32 MFMA K-step/tile.
// EPI: 0 = f32 store, 1 = bf16 store, 2 = softplus(acc + bias[n]) -> bf16
template<int EPI>
__global__ __launch_bounds__(256) void gemm_bf16_kernel(
    const u16* __restrict__ A, int lda,
    const u16* __restrict__ B, int ldb,
    void* __restrict__ C, int ldc,
    int N, int K, const float* __restrict__ bias)
{
  __shared__ u16 As[128][40];   // pad: 80B row stride (16B aligned, 8-bank spread)
  __shared__ u16 Bs[128][40];
  const int tid = threadIdx.x;
  const int row0 = blockIdx.y * 128;
  const int col0 = blockIdx.x * 128;
  const int wave = tid >> 6, lane = tid & 63;
  const int wr = (wave >> 1) * 64;   // wave row offset in tile
  const int wc = (wave & 1) * 64;    // wave col offset in tile
  const int lr = lane & 15, lk = lane >> 4;

  f32x4 acc[4][4] = {};

  for (int k0 = 0; k0 < K; k0 += 32) {
    __syncthreads();
    #pragma unroll
    for (int s = 0; s < 2; ++s) {
      const int slot = tid + s * 256;           // 512 slots of 8 bf16 (16B)
      const int r = slot >> 2, c8 = (slot & 3) << 3;
      *(int4*)&As[r][c8] = *(const int4*)(A + (size_t)(row0 + r) * lda + k0 + c8);
      const int nr = col0 + r;
      int4 bv = {0, 0, 0, 0};
      if (nr < N) bv = *(const int4*)(B + (size_t)nr * ldb + k0 + c8);
      *(int4*)&Bs[r][c8] = bv;
    }
    __syncthreads();
    bf16x8 af[4], bfr[4];
    #pragma unroll
    for (int i = 0; i < 4; ++i) {
      af[i]  = *(const bf16x8*)&As[wr + i * 16 + lr][lk * 8];  // A[m][k..k+7]
      bfr[i] = *(const bf16x8*)&Bs[wc + i * 16 + lr][lk * 8];  // B^T[n][k..k+7]
    }
    #pragma unroll
    for (int i = 0; i < 4; ++i)
      #pragma unroll
      for (int j = 0; j < 4; ++j)
        acc[i][j] = __builtin_amdgcn_mfma_f32_16x16x32_bf16(af[i], bfr[j], acc[i][j], 0, 0, 0);
  }

  // C/D layout (HW-verified): col = lane&15, row = (lane>>4)*4 + reg
  #pragma unroll
  for (int i = 0; i < 4; ++i) {
    #pragma unroll
    for (int j = 0; j < 4; ++j) {
      #pragma unroll
      for (int q = 0; q < 4; ++q) {
        const int r = row0 + wr + i * 16 + lk * 4 + q;
        const int c = col0 + wc + j * 16 + lr;
        if (c < N) {
          float v = acc[i][j][q];
          const size_t o = (size_t)r * ldc + c;
          if (EPI == 0) {
            ((float*)C)[o] = v;
          } else if (EPI == 1) {
            ((u16*)C)[o] = f2bf(v);
          } else {
            v += bias[c];
            v = (v > 20.f) ? v : log1pf(__expf(v));
            ((u16*)C)[o] = f2bf(v);
          }
        }
      }
    }
  }
}

// ---------------- depthwise causal conv1d (k=4) + SiLU ----------------
__global__ __launch_bounds__(256) void conv_silu_kernel(
    const u16* __restrict__ xz, const float* __restrict__ cw,
    const float* __restrict__ cb, u16* __restrict__ u)
{
  const int idx = blockIdx.x * 256 + threadIdx.x;  // BL_TOT * 256 threads
  const int d4 = (idx & 255) << 2;
  const int bl = idx >> 8;            // b*L + t
  const int t = bl & (LSEQ - 1);
  float a0 = cb[d4], a1 = cb[d4 + 1], a2 = cb[d4 + 2], a3 = cb[d4 + 3];
  #pragma unroll
  for (int k = 0; k < 4; ++k) {
    const int tt = t - 3 + k;
    if (tt < 0) continue;
    const uint2 xv = *(const uint2*)(xz + (size_t)(bl - 3 + k) * 2048 + d4);
    a0 += __uint_as_float(xv.x << 16)         * cw[(d4 + 0) * 4 + k];
    a1 += __uint_as_float(xv.x & 0xffff0000u) * cw[(d4 + 1) * 4 + k];
    a2 += __uint_as_float(xv.y << 16)         * cw[(d4 + 2) * 4 + k];
    a3 += __uint_as_float(xv.y & 0xffff0000u) * cw[(d4 + 3) * 4 + k];
  }
  a0 = a0 / (1.f + __expf(-a0));
  a1 = a1 / (1.f + __expf(-a1));
  a2 = a2 / (1.f + __expf(-a2));
  a3 = a3 / (1.f + __expf(-a3));
  uint2 o;
  o.x = (u32)f2bf(a0) | ((u32)f2bf(a1) << 16);
  o.y = (u32)f2bf(a2) | ((u32)f2bf(a3) << 16);
  *(uint2*)(u + (size_t)bl * 1024 + d4) = o;
}

// ---------------- selective scan, chunked (32 chunks x 64) ----------------
// One thread per (chunk, b, d) channel: all 16 states in registers.
// Lanes = consecutive d -> dt/ut/z loads 128B-coalesced; B/C uniform per block.
__global__ __launch_bounds__(256) void scan_pass1(
    const u16* __restrict__ delta, const u16* __restrict__ u,
    const float* __restrict__ xdf, const float* __restrict__ A_log,
    float* __restrict__ hend, float* __restrict__ sumdelta)
{
  const int blk = blockIdx.x;        // 32 chunks * 16 groups
  const int chunk = blk >> 4;
  const int ch = (blk & 15) * 256 + threadIdx.x;   // b*1024 + d
  const int b = ch >> 10, d = ch & 1023;
  float A[16];
  {
    const float4* ap = (const float4*)(A_log + d * 16);
    #pragma unroll
    for (int q = 0; q < 4; ++q) {
      const float4 a = ap[q];
      A[4*q+0] = -__expf(a.x); A[4*q+1] = -__expf(a.y);
      A[4*q+2] = -__expf(a.z); A[4*q+3] = -__expf(a.w);
    }
  }
  float h[16] = {};
  float sumd = 0.f;
  const size_t base = (size_t)b * LSEQ + chunk * CHLEN;
  const u16* dp = delta + base * 1024 + d;
  const u16* up = u + base * 1024 + d;
  const float* xd = xdf + base * 64;
  for (int t = 0; t < CHLEN; ++t) {
    const float dt = bf2f(dp[(size_t)t * 1024]);
    const float ut = bf2f(up[(size_t)t * 1024]);
    const float du = dt * ut;
    float Bn[16];
    const float4* bv = (const float4*)(xd + (size_t)t * 64 + 32);
    #pragma unroll
    for (int q = 0; q < 4; ++q) *(float4*)&Bn[4*q] = bv[q];
    #pragma unroll
    for (int n = 0; n < 16; ++n)
      h[n] = h[n] * __expf(dt * A[n]) + du * Bn[n];
    sumd += dt;
  }
  float* he = hend + ((size_t)ch * NCHUNK + chunk) * 16;
  #pragma unroll
  for (int q = 0; q < 4; ++q) *(float4*)&he[4*q] = *(const float4*)&h[4*q];
  sumdelta[(size_t)ch * NCHUNK + chunk] = sumd;
}

// pass2: sequential chunk-stitch, IN PLACE (buf: hend in, hinit out)
__global__ __launch_bounds__(256) void scan_pass2(
    const float* __restrict__ A_log, const float* __restrict__ sumdelta,
    float* __restrict__ buf)
{
  const int idx = blockIdx.x * 256 + threadIdx.x;  // 65536 = 4096 ch * 16 n
  const int ch = idx >> 4, n = idx & 15;
  const int d = ch & 1023;
  const float A = -__expf(A_log[d * 16 + n]);
  float h = 0.f;
  for (int c = 0; c < NCHUNK; ++c) {
    const size_t o = (size_t)ch * NCHUNK + c;
    const float he = buf[o * 16 + n];
    const float e = __expf(A * sumdelta[o]);
    buf[o * 16 + n] = h;       // hinit for chunk c
    h = e * h + he;
  }
}

// pass3: recompute with correct h_init; y = (<h,C> + u*D) * silu(z) -> bf16
// NOTE: y aliases delta (read-before-write per element within the same thread).
__global__ __launch_bounds__(256) void scan_pass3(
    const u16* __restrict__ delta, const u16* __restrict__ u,
    const float* __restrict__ xdf, const u16* __restrict__ xz,
    const float* __restrict__ A_log, const float* __restrict__ Dvec,
    const float* __restrict__ hinit, u16* __restrict__ y)
{
  const int blk = blockIdx.x;
  const int chunk = blk >> 4;
  const int ch = (blk & 15) * 256 + threadIdx.x;
  const int b = ch >> 10, d = ch & 1023;
  float A[16];
  {
    const float4* ap = (const float4*)(A_log + d * 16);
    #pragma unroll
    for (int q = 0; q < 4; ++q) {
      const float4 a = ap[q];
      A[4*q+0] = -__expf(a.x); A[4*q+1] = -__expf(a.y);
      A[4*q+2] = -__expf(a.z); A[4*q+3] = -__expf(a.w);
    }
  }
  float h[16];
  {
    const float4* hi = (const float4*)(hinit + ((size_t)ch * NCHUNK + chunk) * 16);
    #pragma unroll
    for (int q = 0; q < 4; ++q) *(float4*)&h[4*q] = hi[q];
  }
  const float Dd = Dvec[d];
  const size_t base = (size_t)b * LSEQ + chunk * CHLEN;
  const u16* dp = delta + base * 1024 + d;
  const u16* up = u + base * 1024 + d;
  const float* xd = xdf + base * 64;
  const u16* zp = xz + base * 2048 + 1024 + d;
  u16* yp = y + base * 1024 + d;
  for (int t = 0; t < CHLEN; ++t) {
    const float dt = bf2f(dp[(size_t)t * 1024]);
    const float ut = bf2f(up[(size_t)t * 1024]);
    const float du = dt * ut;
    float Bn[16], Cn[16];
    {
      const float4* bv = (const float4*)(xd + (size_t)t * 64 + 32);
      #pragma unroll
      for (int q = 0; q < 4; ++q) *(float4*)&Bn[4*q] = bv[q];
      #pragma unroll
      for (int q = 0; q < 4; ++q) *(float4*)&Cn[4*q] = bv[q + 4];
    }
    float av[4] = {};
    #pragma unroll
    for (int n = 0; n < 16; ++n) {
      h[n] = h[n] * __expf(dt * A[n]) + du * Bn[n];
      av[n & 3] += h[n] * Cn[n];
    }
    const float pv = (av[0] + av[1]) + (av[2] + av[3]);
    const float z = bf2f(zp[(size_t)t * 2048]);
    const float yy = (pv + ut * Dd) * (z / (1.f + __expf(-z)));
    yp[(size_t)t * 1024] = f2bf(yy);
  }
}

extern "C" void kernel_launch(void* const* d_in, const int* in_sizes, int n_in,
                              void* d_out, int out_size, void* d_ws, size_t ws_size,
                              hipStream_t stream)
{
  (void)in_sizes; (void)n_in; (void)out_size; (void)ws_size;
  const float* hs    = (const float*)d_in[0];
  const float* Win   = (const float*)d_in[1];
  const float* convw = (const float*)d_in[2];
  const float* convb = (const float*)d_in[3];
  const float* Wx    = (const float*)d_in[4];
  const float* Wdt   = (const float*)d_in[5];
  const float* bdt   = (const float*)d_in[6];
  const float* Alog  = (const float*)d_in[7];
  const float* Dv    = (const float*)d_in[8];
  const float* Wout  = (const float*)d_in[9];

  char* p = (char*)d_ws;
  auto take = [&](size_t bytes) -> char* {
    char* r = p; p += (bytes + 255) & ~(size_t)255; return r;
  };
  u16* hs_bf    = (u16*)take((size_t)BL_TOT * 512 * 2);   // 8 MB (dead after K1)
  u16* win_bf   = (u16*)take((size_t)2048 * 512 * 2);     // 2 MB (dead after K1)
  u16* wx_bf    = (u16*)take((size_t)64 * 1024 * 2);
  u16* wdt_bf   = (u16*)take((size_t)1024 * 32 * 2);
  u16* wout_bf  = (u16*)take((size_t)512 * 1024 * 2);
  u16* xz_bf    = (u16*)take((size_t)BL_TOT * 2048 * 2);
  u16* u_bf     = (u16*)take((size_t)BL_TOT * 1024 * 2);
  u16* xdbl_bf  = (u16*)take((size_t)BL_TOT * 64 * 2);
  u16* delta_bf = (u16*)take((size_t)BL_TOT * 1024 * 2);
  float* xdbl_f = (float*)take((size_t)BL_TOT * 64 * 4);
  u16* y_bf     = delta_bf;  // alias (read-before-write per element)
  // scan state buffers alias dead regions (hs_bf: 8 MB == hend exactly)
  float* hend   = (float*)hs_bf;     // NCHUNK*4096*16*4 = 8 MB
  float* sumd   = (float*)win_bf;    // NCHUNK*4096*4 = 0.5 MB (< 2 MB)

  // input casts to bf16
  cast_f32_bf16_kernel<<<4096, 256, 0, stream>>>(hs, hs_bf, BL_TOT * 512 / 4);
  cast_f32_bf16_kernel<<<1024, 256, 0, stream>>>(Win, win_bf, 2048 * 512 / 4);
  cast_f32_bf16_kernel<<<64, 256, 0, stream>>>(Wx, wx_bf, 64 * 1024 / 4);
  cast_f32_bf16_kernel<<<32, 256, 0, stream>>>(Wdt, wdt_bf, 1024 * 32 / 4);
  cast_f32_bf16_kernel<<<512, 256, 0, stream>>>(Wout, wout_bf, 512 * 1024 / 4);

  // K1: xz = hs @ Win^T   (8192 x 2048, K=512)
  gemm_bf16_kernel<1><<<dim3(16, 64), 256, 0, stream>>>(
      hs_bf, 512, win_bf, 512, xz_bf, 2048, 2048, 512, nullptr);
  // conv + silu -> u (8192 x 1024)
  conv_silu_kernel<<<BL_TOT, 256, 0, stream>>>(xz_bf, convw, convb, u_bf);
  // x_dbl = u @ Wx^T (8192 x 64, K=1024)
  gemm_bf16_kernel<1><<<dim3(1, 64), 256, 0, stream>>>(
      u_bf, 1024, wx_bf, 1024, xdbl_bf, 64, 64, 1024, nullptr);
  // x_dbl -> f32 for the scan's B/C
  cast_bf16_f32_kernel<<<512, 256, 0, stream>>>(xdbl_bf, xdbl_f, BL_TOT * 64 / 4);
  // delta = softplus(dt_low @ Wdt^T + b_dt) (8192 x 1024, K=32)
  gemm_bf16_kernel<2><<<dim3(8, 64), 256, 0, stream>>>(
      xdbl_bf, 64, wdt_bf, 32, delta_bf, 1024, 1024, 32, bdt);
  // selective scan (chunked, registers hold all 16 states)
  scan_pass1<<<512, 256, 0, stream>>>(delta_bf, u_bf, xdbl_f, Alog, hend, sumd);
  scan_pass2<<<256, 256, 0, stream>>>(Alog, sumd, hend);   // in-place -> hinit
  scan_pass3<<<512, 256, 0, stream>>>(delta_bf, u_bf, xdbl_f, xz_bf, Alog, Dv, hend, y_bf);
  // out = y @ Wout^T (8192 x 512, K=1024) -> f32
  gemm_bf16_kernel<0><<<dim3(4, 64), 256, 0, stream>>>(
      y_bf, 1024, wout_bf, 1024, d_out, 512, 512, 1024, nullptr);
}

// Round 3
// 300.303 us; speedup vs baseline: 1.6336x; 1.2979x over previous
//
#include <hip/hip_runtime.h>
#include <math.h>

typedef unsigned short u16;
typedef unsigned int u32;
typedef __bf16 bf16x8 __attribute__((ext_vector_type(8)));
typedef float f32x4 __attribute__((ext_vector_type(4)));

// B=4, L=2048, D_MODEL=512, D_INNER=1024, D_STATE=16, D_CONV=4, DT_RANK=32
#define LSEQ 2048
#define BL_TOT 8192            // B*L
#define NCHUNK 32
#define CHLEN 64

__device__ __forceinline__ float bf2f(u16 h) { return __uint_as_float(((u32)h) << 16); }
__device__ __forceinline__ u16 f2bf(float f) {
  u32 u = __float_as_uint(f);
  u32 r = (u + 0x7fffu + ((u >> 16) & 1u)) >> 16;
  return (u16)r;
}

// async global->LDS, 16B per lane (lds dest = wave-uniform base + lane*16)
__device__ __forceinline__ void async_cp16(const void* g, void* l) {
  __builtin_amdgcn_global_load_lds(
      (const __attribute__((address_space(1))) unsigned int*)g,
      (__attribute__((address_space(3))) unsigned int*)l, 16, 0, 0);
}

// ---------------- cast f32 -> bf16 (vector x4) ----------------
__global__ __launch_bounds__(256) void cast_f32_bf16_kernel(
    const float* __restrict__ in, u16* __restrict__ out, int n4)
{
  const int i = blockIdx.x * 256 + threadIdx.x;
  if (i >= n4) return;
  const float4 v = ((const float4*)in)[i];
  uint2 o;
  o.x = (u32)f2bf(v.x) | ((u32)f2bf(v.y) << 16);
  o.y = (u32)f2bf(v.z) | ((u32)f2bf(v.w) << 16);
  ((uint2*)out)[i] = o;
}

// ---------------- cast bf16 -> f32 (vector x4) ----------------
__global__ __launch_bounds__(256) void cast_bf16_f32_kernel(
    const u16* __restrict__ in, float* __restrict__ out, int n4)
{
  const int i = blockIdx.x * 256 + threadIdx.x;
  if (i >= n4) return;
  const uint2 v = ((const uint2*)in)[i];
  float4 o;
  o.x = __uint_as_float(v.x << 16);
  o.y = __uint_as_float(v.x & 0xffff0000u);
  o.z = __uint_as_float(v.y << 16);
  o.w = __uint_as_float(v.y & 0xffff0000u);
  ((float4*)out)[i] = o;
}

// ---------------- bf16 MFMA GEMM: C[M,N] = A[M,K] * B[N,K]^T ----------------
// 128x128 tile, 4 waves (2x2 of 64x64), BK=32, global_load_lds x16 staging
// (m97 structure: linear LDS [128][32] u16, 64B rows).
// EPI: 0 = f32 store, 1 = bf16 store, 2 = softplus(acc + bias[n]) -> bf16
template<int EPI>
__global__ __launch_bounds__(256) void gemm_bf16_kernel(
    const u16* __restrict__ A, int lda,
    const u16* __restrict__ B, int ldb,
    void* __restrict__ C, int ldc,
    int N, int K, const float* __restrict__ bias)
{
  __shared__ alignas(1024) u16 As[128][32];   // 8KB, linear (64B rows)
  __shared__ alignas(1024) u16 Bs[128][32];
  const int tid = threadIdx.x;
  const int row0 = blockIdx.y * 128;
  const int col0 = blockIdx.x * 128;
  const int wave = tid >> 6, lane = tid & 63;
  const int wr = (wave >> 1) * 64;   // wave row offset in tile
  const int wc = (wave & 1) * 64;    // wave col offset in tile
  const int lr = lane & 15, lk = lane >> 4;

  // staging geometry: wave w covers rows [w*32, w*32+32), 2 instrs of 1KB
  const int srow = wave * 32 + (lane >> 2);    // + s*16 rows for s=1
  const int scol = (lane & 3) * 8;
  const u16* ag0 = A + (size_t)(row0 + srow) * lda + scol;
  const u16* ag1 = A + (size_t)(row0 + srow + 16) * lda + scol;
  const u16* bg0 = B + (size_t)(col0 + srow) * ldb + scol;
  const u16* bg1 = B + (size_t)(col0 + srow + 16) * ldb + scol;
  u16* al0 = &As[0][0] + wave * 1024;          // bytes: wave*2048
  u16* al1 = &As[0][0] + wave * 1024 + 512;
  u16* bl0 = &Bs[0][0] + wave * 1024;
  u16* bl1 = &Bs[0][0] + wave * 1024 + 512;

  f32x4 acc[4][4] = {};

  for (int k0 = 0; k0 < K; k0 += 32) {
    __syncthreads();
    async_cp16(ag0 + k0, al0);
    async_cp16(ag1 + k0, al1);
    async_cp16(bg0 + k0, bl0);
    async_cp16(bg1 + k0, bl1);
    __syncthreads();
    bf16x8 af[4], bfr[4];
    #pragma unroll
    for (int i = 0; i < 4; ++i) {
      af[i]  = *(const bf16x8*)&As[wr + i * 16 + lr][lk * 8];  // A[m][k..k+7]
      bfr[i] = *(const bf16x8*)&Bs[wc + i * 16 + lr][lk * 8];  // B^T[n][k..k+7]
    }
    #pragma unroll
    for (int i = 0; i < 4; ++i)
      #pragma unroll
      for (int j = 0; j < 4; ++j)
        acc[i][j] = __builtin_amdgcn_mfma_f32_16x16x32_bf16(af[i], bfr[j], acc[i][j], 0, 0, 0);
  }

  // C/D layout (HW-verified): col = lane&15, row = (lane>>4)*4 + reg
  #pragma unroll
  for (int i = 0; i < 4; ++i) {
    #pragma unroll
    for (int j = 0; j < 4; ++j) {
      #pragma unroll
      for (int q = 0; q < 4; ++q) {
        const int r = row0 + wr + i * 16 + lk * 4 + q;
        const int c = col0 + wc + j * 16 + lr;
        if (c < N) {
          float v = acc[i][j][q];
          const size_t o = (size_t)r * ldc + c;
          if (EPI == 0) {
            ((float*)C)[o] = v;
          } else if (EPI == 1) {
            ((u16*)C)[o] = f2bf(v);
          } else {
            v += bias[c];
            v = (v > 20.f) ? v : log1pf(__expf(v));
            ((u16*)C)[o] = f2bf(v);
          }
        }
      }
    }
  }
}

// ---------------- depthwise causal conv1d (k=4) + SiLU ----------------
__global__ __launch_bounds__(256) void conv_silu_kernel(
    const u16* __restrict__ xz, const float* __restrict__ cw,
    const float* __restrict__ cb, u16* __restrict__ u)
{
  const int idx = blockIdx.x * 256 + threadIdx.x;  // BL_TOT * 256 threads
  const int d4 = (idx & 255) << 2;
  const int bl = idx >> 8;            // b*L + t
  const int t = bl & (LSEQ - 1);
  float a0 = cb[d4], a1 = cb[d4 + 1], a2 = cb[d4 + 2], a3 = cb[d4 + 3];
  #pragma unroll
  for (int k = 0; k < 4; ++k) {
    const int tt = t - 3 + k;
    if (tt < 0) continue;
    const uint2 xv = *(const uint2*)(xz + (size_t)(bl - 3 + k) * 2048 + d4);
    a0 += __uint_as_float(xv.x << 16)         * cw[(d4 + 0) * 4 + k];
    a1 += __uint_as_float(xv.x & 0xffff0000u) * cw[(d4 + 1) * 4 + k];
    a2 += __uint_as_float(xv.y << 16)         * cw[(d4 + 2) * 4 + k];
    a3 += __uint_as_float(xv.y & 0xffff0000u) * cw[(d4 + 3) * 4 + k];
  }
  a0 = a0 / (1.f + __expf(-a0));
  a1 = a1 / (1.f + __expf(-a1));
  a2 = a2 / (1.f + __expf(-a2));
  a3 = a3 / (1.f + __expf(-a3));
  uint2 o;
  o.x = (u32)f2bf(a0) | ((u32)f2bf(a1) << 16);
  o.y = (u32)f2bf(a2) | ((u32)f2bf(a3) << 16);
  *(uint2*)(u + (size_t)bl * 1024 + d4) = o;
}

// ---------------- selective scan, chunked (32 chunks x 64) ----------------
// 4 lanes per (chunk,b,d) channel; quad = lane&3 owns states [quad*4, quad*4+4).
// Lanes: 16 consecutive d x 4 quads per wave -> dt/ut loads coalesce per quad-group.
__global__ __launch_bounds__(256) void scan_pass1(
    const u16* __restrict__ delta, const u16* __restrict__ u,
    const float* __restrict__ xdf, const float* __restrict__ A_log,
    float* __restrict__ hend, float* __restrict__ sumdelta)
{
  const int blk = blockIdx.x;          // 2048 = 32 chunks * 64 groups
  const int chunk = blk >> 6;
  const int ch = (blk & 63) * 64 + (threadIdx.x >> 2);   // b*1024 + d
  const int quad = threadIdx.x & 3;
  const int b = ch >> 10, d = ch & 1023;
  float A[4];
  {
    const float4 a = *(const float4*)(A_log + d * 16 + quad * 4);
    A[0] = -__expf(a.x); A[1] = -__expf(a.y);
    A[2] = -__expf(a.z); A[3] = -__expf(a.w);
  }
  float h[4] = {};
  float sumd = 0.f;
  const size_t base = (size_t)b * LSEQ + chunk * CHLEN;
  const u16* dp = delta + base * 1024 + d;
  const u16* up = u + base * 1024 + d;
  const float* bp = xdf + base * 64 + 32 + quad * 4;
  #pragma unroll 2
  for (int t = 0; t < CHLEN; ++t) {
    const float dt = bf2f(dp[(size_t)t * 1024]);
    const float ut = bf2f(up[(size_t)t * 1024]);
    const float du = dt * ut;
    const float4 Bn = *(const float4*)(bp + (size_t)t * 64);
    h[0] = h[0] * __expf(dt * A[0]) + du * Bn.x;
    h[1] = h[1] * __expf(dt * A[1]) + du * Bn.y;
    h[2] = h[2] * __expf(dt * A[2]) + du * Bn.z;
    h[3] = h[3] * __expf(dt * A[3]) + du * Bn.w;
    sumd += dt;
  }
  float4* he = (float4*)(hend + ((size_t)ch * NCHUNK + chunk) * 16 + quad * 4);
  *he = make_float4(h[0], h[1], h[2], h[3]);
  if (quad == 0) sumdelta[(size_t)ch * NCHUNK + chunk] = sumd;
}

// pass2: sequential chunk-stitch, IN PLACE (buf: hend in, hinit out)
__global__ __launch_bounds__(256) void scan_pass2(
    const float* __restrict__ A_log, const float* __restrict__ sumdelta,
    float* __restrict__ buf)
{
  const int idx = blockIdx.x * 256 + threadIdx.x;  // 65536 = 4096 ch * 16 n
  const int ch = idx >> 4, n = idx & 15;
  const int d = ch & 1023;
  const float A = -__expf(A_log[d * 16 + n]);
  float h = 0.f;
  for (int c = 0; c < NCHUNK; ++c) {
    const size_t o = (size_t)ch * NCHUNK + c;
    const float he = buf[o * 16 + n];
    const float e = __expf(A * sumdelta[o]);
    buf[o * 16 + n] = h;       // hinit for chunk c
    h = e * h + he;
  }
}

// pass3: recompute with correct h_init; y = (<h,C> + u*D) * silu(z) -> bf16
// NOTE: y aliases delta. Safe: each same-address read/write pair is within one
// wave with a data dependence (dp[t] load -> dot -> yp[t] store).
__global__ __launch_bounds__(256) void scan_pass3(
    const u16* __restrict__ delta, const u16* __restrict__ u,
    const float* __restrict__ xdf, const u16* __restrict__ xz,
    const float* __restrict__ A_log, const float* __restrict__ Dvec,
    const float* __restrict__ hinit, u16* __restrict__ y)
{
  const int blk = blockIdx.x;
  const int chunk = blk >> 6;
  const int ch = (blk & 63) * 64 + (threadIdx.x >> 2);
  const int quad = threadIdx.x & 3;
  const int b = ch >> 10, d = ch & 1023;
  float A[4];
  {
    const float4 a = *(const float4*)(A_log + d * 16 + quad * 4);
    A[0] = -__expf(a.x); A[1] = -__expf(a.y);
    A[2] = -__expf(a.z); A[3] = -__expf(a.w);
  }
  float h[4];
  {
    const float4 hi = *(const float4*)(hinit + ((size_t)ch * NCHUNK + chunk) * 16 + quad * 4);
    h[0] = hi.x; h[1] = hi.y; h[2] = hi.z; h[3] = hi.w;
  }
  const float Dd = Dvec[d];
  const size_t base = (size_t)b * LSEQ + chunk * CHLEN;
  const u16* dp = delta + base * 1024 + d;
  const u16* up = u + base * 1024 + d;
  const float* bp = xdf + base * 64 + 32 + quad * 4;
  const float* cp = xdf + base * 64 + 48 + quad * 4;
  const u16* zp = xz + base * 2048 + 1024 + d;
  u16* yp = y + base * 1024 + d;
  #pragma unroll 2
  for (int t = 0; t < CHLEN; ++t) {
    const float dt = bf2f(dp[(size_t)t * 1024]);
    const float ut = bf2f(up[(size_t)t * 1024]);
    const float du = dt * ut;
    const float4 Bn = *(const float4*)(bp + (size_t)t * 64);
    const float4 Cn = *(const float4*)(cp + (size_t)t * 64);
    h[0] = h[0] * __expf(dt * A[0]) + du * Bn.x;
    h[1] = h[1] * __expf(dt * A[1]) + du * Bn.y;
    h[2] = h[2] * __expf(dt * A[2]) + du * Bn.z;
    h[3] = h[3] * __expf(dt * A[3]) + du * Bn.w;
    float pv = (h[0] * Cn.x + h[1] * Cn.y) + (h[2] * Cn.z + h[3] * Cn.w);
    pv += __shfl_xor(pv, 1);
    pv += __shfl_xor(pv, 2);
    if (quad == 0) {
      const float z = bf2f(zp[(size_t)t * 2048]);
      const float yy = (pv + ut * Dd) * (z / (1.f + __expf(-z)));
      yp[(size_t)t * 1024] = f2bf(yy);
    }
  }
}

extern "C" void kernel_launch(void* const* d_in, const int* in_sizes, int n_in,
                              void* d_out, int out_size, void* d_ws, size_t ws_size,
                              hipStream_t stream)
{
  (void)in_sizes; (void)n_in; (void)out_size; (void)ws_size;
  const float* hs    = (const float*)d_in[0];
  const float* Win   = (const float*)d_in[1];
  const float* convw = (const float*)d_in[2];
  const float* convb = (const float*)d_in[3];
  const float* Wx    = (const float*)d_in[4];
  const float* Wdt   = (const float*)d_in[5];
  const float* bdt   = (const float*)d_in[6];
  const float* Alog  = (const float*)d_in[7];
  const float* Dv    = (const float*)d_in[8];
  const float* Wout  = (const float*)d_in[9];

  char* p = (char*)d_ws;
  auto take = [&](size_t bytes) -> char* {
    char* r = p; p += (bytes + 255) & ~(size_t)255; return r;
  };
  u16* hs_bf    = (u16*)take((size_t)BL_TOT * 512 * 2);   // 8 MB (dead after K1)
  u16* win_bf   = (u16*)take((size_t)2048 * 512 * 2);     // 2 MB (dead after K1)
  u16* wx_bf    = (u16*)take((size_t)64 * 1024 * 2);
  u16* wdt_bf   = (u16*)take((size_t)1024 * 32 * 2);
  u16* wout_bf  = (u16*)take((size_t)512 * 1024 * 2);
  u16* xz_bf    = (u16*)take((size_t)BL_TOT * 2048 * 2);
  u16* u_bf     = (u16*)take((size_t)BL_TOT * 1024 * 2);
  u16* xdbl_bf  = (u16*)take((size_t)BL_TOT * 64 * 2);
  u16* delta_bf = (u16*)take((size_t)BL_TOT * 1024 * 2);
  float* xdbl_f = (float*)take((size_t)BL_TOT * 64 * 4);
  u16* y_bf     = delta_bf;  // alias (read-before-write, intra-wave dataflow)
  // scan state buffers alias dead regions (hs_bf: 8 MB == hend exactly)
  float* hend   = (float*)hs_bf;     // NCHUNK*4096*16*4 = 8 MB
  float* sumd   = (float*)win_bf;    // NCHUNK*4096*4 = 0.5 MB (< 2 MB)

  // input casts to bf16
  cast_f32_bf16_kernel<<<4096, 256, 0, stream>>>(hs, hs_bf, BL_TOT * 512 / 4);
  cast_f32_bf16_kernel<<<1024, 256, 0, stream>>>(Win, win_bf, 2048 * 512 / 4);
  cast_f32_bf16_kernel<<<64, 256, 0, stream>>>(Wx, wx_bf, 64 * 1024 / 4);
  cast_f32_bf16_kernel<<<32, 256, 0, stream>>>(Wdt, wdt_bf, 1024 * 32 / 4);
  cast_f32_bf16_kernel<<<512, 256, 0, stream>>>(Wout, wout_bf, 512 * 1024 / 4);

  // K1: xz = hs @ Win^T   (8192 x 2048, K=512)
  gemm_bf16_kernel<1><<<dim3(16, 64), 256, 0, stream>>>(
      hs_bf, 512, win_bf, 512, xz_bf, 2048, 2048, 512, nullptr);
  // conv + silu -> u (8192 x 1024)
  conv_silu_kernel<<<BL_TOT, 256, 0, stream>>>(xz_bf, convw, convb, u_bf);
  // x_dbl = u @ Wx^T (8192 x 64, K=1024)
  gemm_bf16_kernel<1><<<dim3(1, 64), 256, 0, stream>>>(
      u_bf, 1024, wx_bf, 1024, xdbl_bf, 64, 64, 1024, nullptr);
  // x_dbl -> f32 for the scan's B/C
  cast_bf16_f32_kernel<<<512, 256, 0, stream>>>(xdbl_bf, xdbl_f, BL_TOT * 64 / 4);
  // delta = softplus(dt_low @ Wdt^T + b_dt) (8192 x 1024, K=32)
  gemm_bf16_kernel<2><<<dim3(8, 64), 256, 0, stream>>>(
      xdbl_bf, 64, wdt_bf, 32, delta_bf, 1024, 1024, 32, bdt);
  // selective scan (chunked, 4 lanes per channel)
  scan_pass1<<<2048, 256, 0, stream>>>(delta_bf, u_bf, xdbl_f, Alog, hend, sumd);
  scan_pass2<<<256, 256, 0, stream>>>(Alog, sumd, hend);   // in-place -> hinit
  scan_pass3<<<2048, 256, 0, stream>>>(delta_bf, u_bf, xdbl_f, xz_bf, Alog, Dv, hend, y_bf);
  // out = y @ Wout^T (8192 x 512, K=1024) -> f32
  gemm_bf16_kernel<0><<<dim3(4, 64), 256, 0, stream>>>(
      y_bf, 1024, wout_bf, 1024, d_out, 512, 512, 1024, nullptr);
}